// Round 9
// baseline (127.837 us; speedup 1.0000x reference)
//
#include <hip/hip_runtime.h>
#include <hip/hip_bf16.h>

#define NS 1000
#define NB 32
#define NK 27
#define HW 65536
// sim = 10*exp(-cd - gd/0.3) + 3*exp(-10*cd)
// gd = Pg_a + Pg_b - 2*(ga.gb)  with Pg = |bf16(ga)|^2  (diag-exact)

// ws layout (float offsets):
//   Tc : bf16 [NB][NS][32] clusters (k27-31 zero)  -> floats [0, 512000)
//   Tg : bf16 [NB][NS][8]  guidance (k3-7 zero)    -> floats [512000, 640000)
//   E  : f32  [NB][NS][4]  {xr, xc, Pg, 0}         -> floats [640000, 768000)
#define OFF_TG 512000
#define OFF_E  640000

typedef __attribute__((ext_vector_type(8))) short short8;
typedef __attribute__((ext_vector_type(4))) float f32x4;

// ---- gather: one thread per (n, i, ch), ch in [0,32) (R6 verbatim) ----
__global__ void crf_gather(const float* __restrict__ guidance,
                           const float* __restrict__ clusters,
                           const int* __restrict__ coords,
                           float* __restrict__ ws) {
    int tid = blockIdx.x * 256 + threadIdx.x;
    if (tid >= NB * NS * 32) return;
    int ch = tid & 31;
    int ni = tid >> 5;
    int n = ni / NS;
    int i = ni - n * NS;
    int r = coords[i];
    int c = coords[NS + i];
    int pix = r * 256 + c;

    __hip_bfloat16* Tc = (__hip_bfloat16*)ws;
    __hip_bfloat16* Tg = (__hip_bfloat16*)(ws + OFF_TG);
    float* E = ws + OFF_E;

    if (ch < NK) {
        float v = __builtin_nontemporal_load(&clusters[((long)n * NK + ch) * HW + pix]);
        Tc[(long)ni * 32 + ch] = __float2bfloat16(v);
    } else if (ch == NK) {
        #pragma unroll
        for (int k = NK; k < 32; ++k)
            Tc[(long)ni * 32 + k] = __float2bfloat16(0.0f);
    } else if (ch < 31) {
        int q = ch - 28;
        float v = guidance[((long)n * 3 + q) * HW + pix];
        Tg[(long)ni * 8 + q] = __float2bfloat16(v);
    } else {
        float p = 0.0f;
        #pragma unroll
        for (int q = 0; q < 3; ++q) {
            float v = guidance[((long)n * 3 + q) * HW + pix];   // L1 hit (same wave)
            float bv = __bfloat162float(__float2bfloat16(v));
            p += bv * bv;
        }
        #pragma unroll
        for (int k = 3; k < 8; ++k)
            Tg[(long)ni * 8 + k] = __float2bfloat16(0.0f);
        float4 e = {(float)r, (float)c, p, 0.0f};
        *(float4*)(E + (long)ni * 4) = e;
    }
}

// ---- main: block = 16 a-rows x ALL 1000 b-cols (full-row write ownership).
// 4 waves, wave w owns b-swath [w*256, w*256+256). Swapped MFMA:
// mfma(bfrag, afrag) -> acc reg r = b-col (4 consecutive), lane&15 = a-row.
// => one f32x4 NT store per tile = full 64B lines, row-contiguous per block.
__global__ __launch_bounds__(256) void crf_main(const float* __restrict__ ws,
                                                float* __restrict__ out) {
    const int n  = blockIdx.y;
    const int a0 = blockIdx.x * 16;
    const int t = threadIdx.x;
    const int w = t >> 6, lane = t & 63;
    const int lr = lane & 15, lg = lane >> 4;

    const __hip_bfloat16* Tc = (const __hip_bfloat16*)ws;
    const __hip_bfloat16* Tg = (const __hip_bfloat16*)(ws + OFF_TG);
    const float* E = ws + OFF_E;

    // a-side (fixed per lane): a = a0 + lr
    const int a = a0 + lr;
    const int ac = a > NS - 1 ? NS - 1 : a;
    const long rowA = (long)n * NS + ac;
    const short8 afC = *(const short8*)(Tc + rowA * 32 + lg * 8);
    short8 afG = {0, 0, 0, 0, 0, 0, 0, 0};
    if (lg == 0) afG = *(const short8*)(Tg + rowA * 8);
    const f32x4 Ea = *(const f32x4*)(E + rowA * 4);
    const bool aok = (a < NS);

    const int bbase = w * 256;
    float* porow = out + ((long)n * NS + a) * NS;   // valid only if aok

    #pragma unroll 4
    for (int ti = 0; ti < 16; ++ti) {
        const int bt = bbase + ti * 16 + lr;
        const int btc = bt > NS - 1 ? NS - 1 : bt;
        const long rowB = (long)n * NS + btc;
        const short8 bfC = *(const short8*)(Tc + rowB * 32 + lg * 8);
        short8 bfG = {0, 0, 0, 0, 0, 0, 0, 0};
        if (lg == 0) bfG = *(const short8*)(Tg + rowB * 8);

        f32x4 z = {0.0f, 0.0f, 0.0f, 0.0f};
        f32x4 accC = __builtin_amdgcn_mfma_f32_16x16x32_bf16(bfC, afC, z, 0, 0, 0);
        f32x4 accG = __builtin_amdgcn_mfma_f32_16x16x32_bf16(bfG, afG, z, 0, 0, 0);

        const int bq = bbase + ti * 16 + 4 * lg;    // first b-col of this lane's quad
        f32x4 res;
        #pragma unroll
        for (int r = 0; r < 4; ++r) {
            int b = bq + r;
            int bcl = b > NS - 1 ? NS - 1 : b;
            const f32x4 Eb = *(const f32x4*)(E + ((long)n * NS + bcl) * 4);
            float dr = Ea.x - Eb.x, dc = Ea.y - Eb.y;
            float cd = dr * dr + dc * dc;
            float gd = Ea.z + Eb.z - 2.0f * accG[r];
            float e1 = __expf(-cd - gd * 3.3333333f);
            float e2 = __expf(-10.0f * cd);
            float sv = fmaf(e1, -10.0f, e2 * -3.0f);   // -(10 e1 + 3 e2)
            res[r] = accC[r] * sv;
        }
        if (aok && bq < NS)
            __builtin_nontemporal_store(res, (f32x4*)(porow + bq));
    }
}

extern "C" void kernel_launch(void* const* d_in, const int* in_sizes, int n_in,
                              void* d_out, int out_size, void* d_ws, size_t ws_size,
                              hipStream_t stream) {
    const float* guidance = (const float*)d_in[0];
    const float* clusters = (const float*)d_in[1];
    const int*   coords   = (const int*)d_in[2];
    float* out = (float*)d_out;
    float* ws  = (float*)d_ws;

    {
        int total = NB * NS * 32;          // 1,024,000
        int blocks = (total + 255) / 256;  // 4000
        crf_gather<<<blocks, 256, 0, stream>>>(guidance, clusters, coords, ws);
    }
    {
        dim3 grid(63, NB);                 // 16 a-rows x full b per block
        crf_main<<<grid, 256, 0, stream>>>(ws, out);
    }
}

// Round 10
// 78.491 us; speedup vs baseline: 1.6287x; 1.6287x over previous
//
#include <hip/hip_runtime.h>

// Problem constants (from reference)
#define NS   1000        // N_SAMPLES
#define NB   32          // batch
#define NK   27          // cluster channels
#define KP   28          // padded K (for float4)
#define HW   65536       // 256*256
// sim = 10*exp(-cd/1.0 - gd/0.3) + 3*exp(-cd/0.1)

// ws layout (floats):
//   selc [NB][NS][KP]  : 896000
//   selg [NB][NS][4]   : 128000   (offset 896000)
//   cf   [NS][2]       : 2000     (offset 1024000)
#define OFF_SELG 896000
#define OFF_CF   1024000

// gather: one thread per (n, i, ch), ch in [0,32)
// NOTE R10: all nontemporal hints REMOVED — let the 61 MB of scattered input
// lines persist in L3 across graph replays (194 MB working set < 256 MB L3).
__global__ void crf_gather(const float* __restrict__ guidance,
                           const float* __restrict__ clusters,
                           const int* __restrict__ coords,
                           float* __restrict__ ws) {
    int tid = blockIdx.x * 256 + threadIdx.x;
    if (tid >= NB * NS * 32) return;
    int ch = tid & 31;
    int ni = tid >> 5;
    int n = ni / NS;
    int i = ni - n * NS;
    int r = coords[i];
    int c = coords[NS + i];
    int pix = r * 256 + c;

    if (ch < KP) {
        float v = 0.0f;
        if (ch < NK)
            v = clusters[((long)n * NK + ch) * HW + pix];
        ws[(long)ni * KP + ch] = v;
    } else {
        int g = ch - KP;  // 0..3
        float v = 0.0f;
        if (g < 3)
            v = guidance[((long)n * 3 + g) * HW + pix];
        ws[OFF_SELG + (long)ni * 4 + g] = v;
        if (g == 3 && n == 0) {
            ws[OFF_CF + i * 2]     = (float)r;
            ws[OFF_CF + i * 2 + 1] = (float)c;
        }
    }
}

#define RA     20          // a-rows per block
#define NCHUNK 50          // NS / RA

__global__ __launch_bounds__(512, 4) void crf_main(const float* __restrict__ ws,
                                                   float* __restrict__ out) {
    const int bid = blockIdx.x;
    const int n = bid / NCHUNK;
    const int a0 = (bid - n * NCHUNK) * RA;
    const int t = threadIdx.x;

    const float* __restrict__ selc = ws;
    const float* __restrict__ selg = ws + OFF_SELG;
    const float* __restrict__ cf   = ws + OFF_CF;

    const int b0 = t;
    const int b1raw = t + 512;
    const int b1 = b1raw < NS ? b1raw : NS - 1;

    float4 cb[2][7];
    float gb0[2], gb1[2], gb2[2], xbr[2], xbc[2];
    {
        const int bs[2] = {b0, b1};
        #pragma unroll
        for (int i = 0; i < 2; ++i) {
            const float4* pc = (const float4*)(selc + ((long)n * NS + bs[i]) * KP);
            #pragma unroll
            for (int j = 0; j < 7; ++j) cb[i][j] = pc[j];
            const float* pg = selg + ((long)n * NS + bs[i]) * 4;
            gb0[i] = pg[0]; gb1[i] = pg[1]; gb2[i] = pg[2];
            xbr[i] = cf[bs[i] * 2]; xbc[i] = cf[bs[i] * 2 + 1];
        }
    }

    const bool w1 = (b1raw < NS);

    for (int a = 0; a < RA; ++a) {
        const int arow = n * NS + a0 + a;          // wave-uniform
        const float4* pa = (const float4*)(selc + (long)arow * KP);
        const float* pg = selg + (long)arow * 4;
        const float ga0 = pg[0], ga1 = pg[1], ga2 = pg[2];
        const float xar = cf[(a0 + a) * 2], xac = cf[(a0 + a) * 2 + 1];

        float dot0 = 0.0f, dot1 = 0.0f;
        #pragma unroll
        for (int j = 0; j < 7; ++j) {
            float4 va = pa[j];                     // uniform -> SGPRs
            dot0 += va.x * cb[0][j].x;  dot1 += va.x * cb[1][j].x;
            dot0 += va.y * cb[0][j].y;  dot1 += va.y * cb[1][j].y;
            dot0 += va.z * cb[0][j].z;  dot1 += va.z * cb[1][j].z;
            dot0 += va.w * cb[0][j].w;  dot1 += va.w * cb[1][j].w;
        }

        float* po = out + (long)arow * NS;
        {
            float g0 = ga0 - gb0[0], g1 = ga1 - gb1[0], g2 = ga2 - gb2[0];
            float gd = g0 * g0 + g1 * g1 + g2 * g2;
            float dr = xar - xbr[0], dc = xac - xbc[0];
            float cd = dr * dr + dc * dc;
            float s = 10.0f * __expf(-cd - gd * (1.0f / 0.3f))
                    +  3.0f * __expf(-10.0f * cd);
            po[b0] = -dot0 * s;
        }
        {
            float g0 = ga0 - gb0[1], g1 = ga1 - gb1[1], g2 = ga2 - gb2[1];
            float gd = g0 * g0 + g1 * g1 + g2 * g2;
            float dr = xar - xbr[1], dc = xac - xbc[1];
            float cd = dr * dr + dc * dc;
            float s = 10.0f * __expf(-cd - gd * (1.0f / 0.3f))
                    +  3.0f * __expf(-10.0f * cd);
            if (w1) po[b1raw] = -dot1 * s;
        }
    }
}

extern "C" void kernel_launch(void* const* d_in, const int* in_sizes, int n_in,
                              void* d_out, int out_size, void* d_ws, size_t ws_size,
                              hipStream_t stream) {
    const float* guidance = (const float*)d_in[0];
    const float* clusters = (const float*)d_in[1];
    const int*   coords   = (const int*)d_in[2];
    float* out = (float*)d_out;
    float* ws  = (float*)d_ws;

    {
        int total = NB * NS * 32;
        int blocks = (total + 255) / 256;
        crf_gather<<<blocks, 256, 0, stream>>>(guidance, clusters, coords, ws);
    }
    {
        int blocks = NB * NCHUNK;   // 1600
        crf_main<<<blocks, 512, 0, stream>>>(ws, out);
    }
}

// Round 11
// 76.495 us; speedup vs baseline: 1.6712x; 1.0261x over previous
//
#include <hip/hip_runtime.h>

// Problem constants (from reference)
#define NS   1000        // N_SAMPLES
#define NB   32          // batch
#define NK   27          // cluster channels
#define KP   28          // padded K (for float4)
#define HW   65536       // 256*256
// sim = 10*exp(-cd/1.0 - gd/0.3) + 3*exp(-cd/0.1)

// ws layout (floats):
//   selc [NB][NS][KP]  : 896000
//   selg [NB][NS][4]   : 128000   (offset 896000)
//   cf   [NS][2]       : 2000     (offset 1024000)
#define OFF_SELG 896000
#define OFF_CF   1024000

// gather: one thread per (n, i, ch), ch in [0,32)
__global__ void crf_gather(const float* __restrict__ guidance,
                           const float* __restrict__ clusters,
                           const int* __restrict__ coords,
                           float* __restrict__ ws) {
    int tid = blockIdx.x * 256 + threadIdx.x;
    if (tid >= NB * NS * 32) return;
    int ch = tid & 31;
    int ni = tid >> 5;
    int n = ni / NS;
    int i = ni - n * NS;
    int r = coords[i];
    int c = coords[NS + i];
    int pix = r * 256 + c;

    if (ch < KP) {
        float v = 0.0f;
        if (ch < NK)
            v = clusters[((long)n * NK + ch) * HW + pix];
        ws[(long)ni * KP + ch] = v;
    } else {
        int g = ch - KP;  // 0..3
        float v = 0.0f;
        if (g < 3)
            v = guidance[((long)n * 3 + g) * HW + pix];
        ws[OFF_SELG + (long)ni * 4 + g] = v;
        if (g == 3 && n == 0) {
            ws[OFF_CF + i * 2]     = (float)r;
            ws[OFF_CF + i * 2 + 1] = (float)c;
        }
    }
}

#define RA     20          // a-rows per block
#define NCHUNK 50          // NS / RA

// main: R10 structure + SOFTWARE-PREFETCHED a-row double buffer.
// Iteration a computes on registers while a+1's row loads are in flight.
__global__ __launch_bounds__(512, 4) void crf_main(const float* __restrict__ ws,
                                                   float* __restrict__ out) {
    const int bid = blockIdx.x;
    const int n = bid / NCHUNK;
    const int a0 = (bid - n * NCHUNK) * RA;
    const int t = threadIdx.x;

    const float* __restrict__ selc = ws;
    const float* __restrict__ selg = ws + OFF_SELG;
    const float* __restrict__ cf   = ws + OFF_CF;

    const int b0 = t;
    const int b1raw = t + 512;
    const int b1 = b1raw < NS ? b1raw : NS - 1;

    float4 cb[2][7];
    float gb0[2], gb1[2], gb2[2], xbr[2], xbc[2];
    {
        const int bs[2] = {b0, b1};
        #pragma unroll
        for (int i = 0; i < 2; ++i) {
            const float4* pc = (const float4*)(selc + ((long)n * NS + bs[i]) * KP);
            #pragma unroll
            for (int j = 0; j < 7; ++j) cb[i][j] = pc[j];
            const float* pg = selg + ((long)n * NS + bs[i]) * 4;
            gb0[i] = pg[0]; gb1[i] = pg[1]; gb2[i] = pg[2];
            xbr[i] = cf[bs[i] * 2]; xbc[i] = cf[bs[i] * 2 + 1];
        }
    }

    const bool w1 = (b1raw < NS);

    // ---- prefetch a-row 0 ----
    float4 pa_nx[7];
    float ga0_nx, ga1_nx, ga2_nx, xar_nx, xac_nx;
    {
        const long arow = (long)n * NS + a0;
        const float4* pa = (const float4*)(selc + arow * KP);
        #pragma unroll
        for (int j = 0; j < 7; ++j) pa_nx[j] = pa[j];
        const float* pg = selg + arow * 4;
        ga0_nx = pg[0]; ga1_nx = pg[1]; ga2_nx = pg[2];
        xar_nx = cf[a0 * 2]; xac_nx = cf[a0 * 2 + 1];
    }

    for (int a = 0; a < RA; ++a) {
        // consume prefetched row
        float4 pa_cur[7];
        #pragma unroll
        for (int j = 0; j < 7; ++j) pa_cur[j] = pa_nx[j];
        const float ga0 = ga0_nx, ga1 = ga1_nx, ga2 = ga2_nx;
        const float xar = xar_nx, xac = xac_nx;

        // issue next row's loads BEFORE compute (latency hidden under FMAs)
        if (a < RA - 1) {
            const long arow = (long)n * NS + a0 + a + 1;
            const float4* pa = (const float4*)(selc + arow * KP);
            #pragma unroll
            for (int j = 0; j < 7; ++j) pa_nx[j] = pa[j];
            const float* pg = selg + arow * 4;
            ga0_nx = pg[0]; ga1_nx = pg[1]; ga2_nx = pg[2];
            xar_nx = cf[(a0 + a + 1) * 2]; xac_nx = cf[(a0 + a + 1) * 2 + 1];
        }

        float dot0 = 0.0f, dot1 = 0.0f;
        #pragma unroll
        for (int j = 0; j < 7; ++j) {
            float4 va = pa_cur[j];
            dot0 += va.x * cb[0][j].x;  dot1 += va.x * cb[1][j].x;
            dot0 += va.y * cb[0][j].y;  dot1 += va.y * cb[1][j].y;
            dot0 += va.z * cb[0][j].z;  dot1 += va.z * cb[1][j].z;
            dot0 += va.w * cb[0][j].w;  dot1 += va.w * cb[1][j].w;
        }

        float* po = out + ((long)n * NS + a0 + a) * NS;
        {
            float g0 = ga0 - gb0[0], g1 = ga1 - gb1[0], g2 = ga2 - gb2[0];
            float gd = g0 * g0 + g1 * g1 + g2 * g2;
            float dr = xar - xbr[0], dc = xac - xbc[0];
            float cd = dr * dr + dc * dc;
            float s = 10.0f * __expf(-cd - gd * (1.0f / 0.3f))
                    +  3.0f * __expf(-10.0f * cd);
            po[b0] = -dot0 * s;
        }
        {
            float g0 = ga0 - gb0[1], g1 = ga1 - gb1[1], g2 = ga2 - gb2[1];
            float gd = g0 * g0 + g1 * g1 + g2 * g2;
            float dr = xar - xbr[1], dc = xac - xbc[1];
            float cd = dr * dr + dc * dc;
            float s = 10.0f * __expf(-cd - gd * (1.0f / 0.3f))
                    +  3.0f * __expf(-10.0f * cd);
            if (w1) po[b1raw] = -dot1 * s;
        }
    }
}

extern "C" void kernel_launch(void* const* d_in, const int* in_sizes, int n_in,
                              void* d_out, int out_size, void* d_ws, size_t ws_size,
                              hipStream_t stream) {
    const float* guidance = (const float*)d_in[0];
    const float* clusters = (const float*)d_in[1];
    const int*   coords   = (const int*)d_in[2];
    float* out = (float*)d_out;
    float* ws  = (float*)d_ws;

    {
        int total = NB * NS * 32;
        int blocks = (total + 255) / 256;
        crf_gather<<<blocks, 256, 0, stream>>>(guidance, clusters, coords, ws);
    }
    {
        int blocks = NB * NCHUNK;   // 1600
        crf_main<<<blocks, 512, 0, stream>>>(ws, out);
    }
}